// Round 1
// 1235.548 us; speedup vs baseline: 1.1543x; 1.1543x over previous
//
#include <hip/hip_runtime.h>

// Problem constants: B=8, C=768, NH=12, WS=8, NC=1, H=W=64
#define B_    8
#define C_    768
#define NH_   12
#define HW_   4096
#define NTOK  4097
#define MTOT  32776         // B_ * NTOK
#define NEGV  (-10000.0f)
#define NSPLIT 16

typedef __bf16 bf16x8 __attribute__((ext_vector_type(8)));
typedef float  f32x4  __attribute__((ext_vector_type(4)));
typedef unsigned short us8 __attribute__((ext_vector_type(8)));

// addrspace casts for global_load_lds
#define GLB(p) ((const __attribute__((address_space(1))) void*)(p))
#define LDS(p) ((__attribute__((address_space(3))) void*)(p))

__device__ __forceinline__ float us2f(unsigned short u) {
    unsigned int v = ((unsigned int)u) << 16;
    float f; __builtin_memcpy(&f, &v, 4);
    return f;
}
__device__ __forceinline__ unsigned short f2us(float f) {
    unsigned int v; __builtin_memcpy(&v, &f, 4);
    v += 0x7FFFu + ((v >> 16) & 1u);   // RNE
    return (unsigned short)(v >> 16);
}

// ---------------------------------------------------------------------------
// Runtime dtype detect (flag=1 -> fp32 inputs). Proven flag=0 (bf16) on the
// harness, but keep the dispatch: ~2 us and known-correct.
// ---------------------------------------------------------------------------
__global__ __launch_bounds__(256) void detect_dtype(
    const unsigned int* __restrict__ xw, int* __restrict__ flag)
{
    __shared__ int s[256];
    int t = threadIdx.x, cnt = 0;
    for (int i = t; i < 4096; i += 256) {
        unsigned e = (xw[i] >> 23) & 0xFFu;
        cnt += (e >= 64u && e <= 191u) ? 1 : 0;
    }
    s[t] = cnt; __syncthreads();
    for (int k = 128; k > 0; k >>= 1) { if (t < k) s[t] += s[t + k]; __syncthreads(); }
    if (t == 0) *flag = (s[0] > 2048) ? 1 : 0;
}

// ---------------------------------------------------------------------------
// Generic weight transpose: src (Kd x Nd, flag dtype) -> dst (Nd x Kd, bf16)
// ---------------------------------------------------------------------------
__global__ __launch_bounds__(256) void transpose_w(
    const unsigned short* __restrict__ s16, const float* __restrict__ s32,
    const int* __restrict__ flagp, unsigned short* __restrict__ dst,
    int Kd, int Nd)
{
    int o = blockIdx.x * 256 + threadIdx.x;
    if (o >= Kd * Nd) return;
    int n = o / Kd, k = o % Kd;
    dst[o] = (*flagp) ? f2us(s32[(size_t)k * Nd + n]) : s16[(size_t)k * Nd + n];
}

// ---------------------------------------------------------------------------
// Fast GEMM, m97 structure: 128x128x32 tile, 4 waves, 16x16x32 bf16 MFMA,
// LINEAR [128][32] LDS tiles staged via global_load_lds dwordx4.
// A: bf16 (or fp32 via wave-uniform fallback branch). BT: Nd x K bf16 always.
// C/D layout, fragment indexing identical to the verified gemm_univ (stride
// 40 -> 32 is the only LDS change).
// ---------------------------------------------------------------------------
__global__ __launch_bounds__(256) void gemm_bt(
    const unsigned short* __restrict__ A16, const float* __restrict__ A32,
    const int* __restrict__ aflagp,
    const unsigned short* __restrict__ BT,
    const unsigned short* __restrict__ bias16, const float* __restrict__ bias32,
    const int* __restrict__ bflagp,
    void* __restrict__ Cout, const int* __restrict__ oflagp,
    int M, int Nd, int K, long arow0)
{
    __shared__ __align__(16) unsigned short As[128 * 32];   // 8 KB
    __shared__ __align__(16) unsigned short Bs[128 * 32];   // 8 KB

    const int fa = aflagp ? *aflagp : 0;
    const int fb = bflagp ? *bflagp : 0;
    const int fo = oflagp ? *oflagp : 0;

    const int t    = threadIdx.x;
    const int m0   = blockIdx.y * 128;
    const int n0   = blockIdx.x * 128;
    const int wave = t >> 6;
    const int lane = t & 63;
    const int wm   = (wave >> 1) * 64;
    const int wn   = (wave & 1) * 64;
    const int frow = lane & 15;
    const int koff = (lane >> 4) * 8;

    f32x4 acc[4][4];
#pragma unroll
    for (int i = 0; i < 4; ++i)
#pragma unroll
        for (int j = 0; j < 4; ++j) acc[i][j] = (f32x4)0.0f;

    // staging geometry: thread t covers row t>>2 (of 64), bf16 cols (t&3)*8
    const int sr = t >> 2;
    const int sc = (t & 3) * 8;

    int ga0 = m0 + sr;       if (ga0 >= M)  ga0 = M - 1;
    int ga1 = m0 + sr + 64;  if (ga1 >= M)  ga1 = M - 1;
    int gb0 = n0 + sr;       if (gb0 >= Nd) gb0 = Nd - 1;
    int gb1 = n0 + sr + 64;  if (gb1 >= Nd) gb1 = Nd - 1;

    const unsigned short* a0p = A16 + (size_t)(arow0 + ga0) * K + sc;
    const unsigned short* a1p = A16 + (size_t)(arow0 + ga1) * K + sc;
    const float*          a0f = A32 + (size_t)(arow0 + ga0) * K + sc;
    const float*          a1f = A32 + (size_t)(arow0 + ga1) * K + sc;
    const unsigned short* b0p = BT + (size_t)gb0 * K + sc;
    const unsigned short* b1p = BT + (size_t)gb1 * K + sc;

    // linear LDS dest: element offset it*2048 + t*8  (= byte it*4096 + t*16)
    unsigned short* asd = &As[t * 8];
    unsigned short* bsd = &Bs[t * 8];

    for (int k0 = 0; k0 < K; k0 += 32) {
        if (fa) {   // fp32 A fallback: register stage + convert (wave-uniform)
            unsigned short tmp[8];
#pragma unroll
            for (int e = 0; e < 8; ++e) tmp[e] = f2us(a0f[k0 + e]);
            *reinterpret_cast<us8*>(&As[sr * 32 + sc]) = *reinterpret_cast<us8*>(tmp);
#pragma unroll
            for (int e = 0; e < 8; ++e) tmp[e] = f2us(a1f[k0 + e]);
            *reinterpret_cast<us8*>(&As[(sr + 64) * 32 + sc]) = *reinterpret_cast<us8*>(tmp);
        } else {
            __builtin_amdgcn_global_load_lds(GLB(a0p + k0), LDS(asd),        16, 0, 0);
            __builtin_amdgcn_global_load_lds(GLB(a1p + k0), LDS(asd + 2048), 16, 0, 0);
        }
        __builtin_amdgcn_global_load_lds(GLB(b0p + k0), LDS(bsd),        16, 0, 0);
        __builtin_amdgcn_global_load_lds(GLB(b1p + k0), LDS(bsd + 2048), 16, 0, 0);
        __syncthreads();

        bf16x8 af[4], bfr[4];
#pragma unroll
        for (int i = 0; i < 4; ++i)
            af[i] = *reinterpret_cast<const bf16x8*>(&As[(wm + i * 16 + frow) * 32 + koff]);
#pragma unroll
        for (int j = 0; j < 4; ++j)
            bfr[j] = *reinterpret_cast<const bf16x8*>(&Bs[(wn + j * 16 + frow) * 32 + koff]);
#pragma unroll
        for (int i = 0; i < 4; ++i)
#pragma unroll
            for (int j = 0; j < 4; ++j)
                acc[i][j] = __builtin_amdgcn_mfma_f32_16x16x32_bf16(af[i], bfr[j], acc[i][j], 0, 0, 0);
        __syncthreads();
    }

    const int crow = (lane >> 4) * 4;
    const int ccol = lane & 15;
    unsigned short* C16 = (unsigned short*)Cout;
    float*          C32 = (float*)Cout;
#pragma unroll
    for (int i = 0; i < 4; ++i)
#pragma unroll
        for (int j = 0; j < 4; ++j) {
            int gn = n0 + wn + j * 16 + ccol;
            float bv = 0.0f;
            if (bias16) bv = fb ? bias32[gn] : us2f(bias16[gn]);
#pragma unroll
            for (int r = 0; r < 4; ++r) {
                int gm = m0 + wm + i * 16 + crow + r;
                if (gm < M) {
                    float v = acc[i][j][r] + bv;
                    if (fo) C32[(size_t)gm * Nd + gn] = v;
                    else    C16[(size_t)gm * Nd + gn] = f2us(v);
                }
            }
        }
}

// ---------------------------------------------------------------------------
// Universal GEMM (kept as fallback for the proj GEMM when ws is too small to
// hold the pre-transposed proj weight). btmode=1: B natural K x Nd, transposed
// during staging.
// ---------------------------------------------------------------------------
#define LSTR 40   // 32+8 pad; 80 B rows, 16B-aligned

__global__ __launch_bounds__(256) void gemm_univ(
    const unsigned short* __restrict__ A16, const float* __restrict__ A32,
    const int* __restrict__ aflagp,
    const unsigned short* __restrict__ B16, const float* __restrict__ B32,
    const int* __restrict__ bflagp, int btmode,
    const unsigned short* __restrict__ bias16, const float* __restrict__ bias32,
    void* __restrict__ Cout, const int* __restrict__ oflagp,
    int M, int Nd, int K, long arow0)
{
    __shared__ __align__(16) unsigned short As[128 * LSTR];
    __shared__ __align__(16) unsigned short Bs[128 * LSTR];

    const int fa = aflagp ? *aflagp : 0;
    const int fb = bflagp ? *bflagp : 0;
    const int fo = oflagp ? *oflagp : 0;

    const int t    = threadIdx.x;
    const int m0   = blockIdx.y * 128;
    const int n0   = blockIdx.x * 128;
    const int wave = t >> 6;
    const int lane = t & 63;
    const int wm   = (wave >> 1) * 64;
    const int wn   = (wave & 1) * 64;
    const int frow = lane & 15;
    const int koff = (lane >> 4) * 8;

    f32x4 acc[4][4];
#pragma unroll
    for (int i = 0; i < 4; ++i)
#pragma unroll
        for (int j = 0; j < 4; ++j) acc[i][j] = (f32x4)0.0f;

    const int sr = t >> 2;
    const int sc = (t & 3) * 8;

    for (int k0 = 0; k0 < K; k0 += 32) {
#pragma unroll
        for (int it = 0; it < 2; ++it) {
            int r = sr + it * 64;
            int gl = m0 + r; if (gl >= M) gl = M - 1;
            size_t grow = (size_t)(arow0 + gl);
            if (fa) {
                const float* p = &A32[grow * K + k0 + sc];
                unsigned short tmp[8];
#pragma unroll
                for (int e = 0; e < 8; ++e) tmp[e] = f2us(p[e]);
                *reinterpret_cast<us8*>(&As[r * LSTR + sc]) = *reinterpret_cast<us8*>(tmp);
            } else {
                *reinterpret_cast<bf16x8*>(&As[r * LSTR + sc]) =
                    *reinterpret_cast<const bf16x8*>(&A16[grow * K + k0 + sc]);
            }
        }
        if (btmode == 0) {
#pragma unroll
            for (int it = 0; it < 2; ++it) {
                int r = sr + it * 64;
                int gn = n0 + r; if (gn >= Nd) gn = Nd - 1;
                *reinterpret_cast<bf16x8*>(&Bs[r * LSTR + sc]) =
                    *reinterpret_cast<const bf16x8*>(&B16[(size_t)gn * K + k0 + sc]);
            }
        } else {
            const int kr = t >> 3;
            const int nc = (t & 7) * 16;
            if (fb) {
                const float* p = &B32[(size_t)(k0 + kr) * Nd + n0 + nc];
#pragma unroll
                for (int e = 0; e < 16; ++e) Bs[(nc + e) * LSTR + kr] = f2us(p[e]);
            } else {
                const unsigned short* p = &B16[(size_t)(k0 + kr) * Nd + n0 + nc];
#pragma unroll
                for (int e = 0; e < 16; ++e) Bs[(nc + e) * LSTR + kr] = p[e];
            }
        }
        __syncthreads();

        bf16x8 af[4], bfr[4];
#pragma unroll
        for (int i = 0; i < 4; ++i)
            af[i] = *reinterpret_cast<const bf16x8*>(&As[(wm + i * 16 + frow) * LSTR + koff]);
#pragma unroll
        for (int j = 0; j < 4; ++j)
            bfr[j] = *reinterpret_cast<const bf16x8*>(&Bs[(wn + j * 16 + frow) * LSTR + koff]);
#pragma unroll
        for (int i = 0; i < 4; ++i)
#pragma unroll
            for (int j = 0; j < 4; ++j)
                acc[i][j] = __builtin_amdgcn_mfma_f32_16x16x32_bf16(af[i], bfr[j], acc[i][j], 0, 0, 0);
        __syncthreads();
    }

    const int crow = (lane >> 4) * 4;
    const int ccol = lane & 15;
    unsigned short* C16 = (unsigned short*)Cout;
    float*          C32 = (float*)Cout;
#pragma unroll
    for (int i = 0; i < 4; ++i)
#pragma unroll
        for (int j = 0; j < 4; ++j) {
            int gn = n0 + wn + j * 16 + ccol;
            float bv = 0.0f;
            if (bias16) bv = fb ? bias32[gn] : us2f(bias16[gn]);
#pragma unroll
            for (int r = 0; r < 4; ++r) {
                int gm = m0 + wm + i * 16 + crow + r;
                if (gm < M) {
                    float v = acc[i][j][r] + bv;
                    if (fo) C32[(size_t)gm * Nd + gn] = v;
                    else    C16[(size_t)gm * Nd + gn] = f2us(v);
                }
            }
        }
}

// ---------------------------------------------------------------------------
// Window attention over a 2-batch qkv slab: block = (window, head, bb).
// ---------------------------------------------------------------------------
__global__ __launch_bounds__(256) void win_attn(
    const unsigned short* __restrict__ qkv2,
    const unsigned short* __restrict__ m16, const float* __restrict__ m32,
    const int* __restrict__ flagp,
    unsigned short* __restrict__ xcat, int b0)
{
    __shared__ __align__(16) unsigned short qs[64 * 64];
    __shared__ __align__(16) unsigned short ks[64 * 64];
    __shared__ __align__(16) unsigned short vs[64 * 64];
    __shared__ float S[64 * 64];
    __shared__ float tok[64];

    const int w  = blockIdx.x;
    const int h  = blockIdx.y;
    const int bb = blockIdx.z;
    const int b  = b0 + bb;
    const int hb = w >> 3, wb = w & 7;
    const int t  = threadIdx.x;
    const int f  = *flagp;
    const unsigned short* qkvb = qkv2 + (size_t)bb * NTOK * 2304;

#define POS(i) ((hb * 8 + ((i) >> 3)) * 64 + wb * 8 + ((i) & 7))

#pragma unroll
    for (int it = 0; it < 2; ++it) {
        int i = (t >> 3) + it * 32;
        int d = (t & 7) * 8;
        size_t row = (size_t)(1 + POS(i)) * 2304;
        *reinterpret_cast<bf16x8*>(&qs[i * 64 + d]) =
            *reinterpret_cast<const bf16x8*>(&qkvb[row + 0    + h * 64 + d]);
        *reinterpret_cast<bf16x8*>(&ks[i * 64 + d]) =
            *reinterpret_cast<const bf16x8*>(&qkvb[row + 768  + h * 64 + d]);
        *reinterpret_cast<bf16x8*>(&vs[i * 64 + d]) =
            *reinterpret_cast<const bf16x8*>(&qkvb[row + 1536 + h * 64 + d]);
    }
    if (t < 64) {
        size_t mi = ((size_t)b * HW_ + POS(t)) * C_;
        tok[t] = f ? m32[mi] : us2f(m16[mi]);
    }
    __syncthreads();

    {
        int i  = t >> 2;
        int j0 = (t & 3) * 16;
        for (int j = j0; j < j0 + 16; ++j) {
            float s = 0.f;
#pragma unroll 8
            for (int d = 0; d < 64; ++d)
                s += us2f(qs[i * 64 + d]) * us2f(ks[j * 64 + d]);
            s *= 0.125f;
            if (tok[i] * tok[j] == 0.0f) s = NEGV;
            S[i * 64 + j] = s;
        }
    }
    __syncthreads();

    if (t < 64) {
        float m = -1e30f;
        for (int j = 0; j < 64; ++j) m = fmaxf(m, S[t * 64 + j]);
        float sum = 0.f;
        for (int j = 0; j < 64; ++j) { float e = __expf(S[t * 64 + j] - m); S[t * 64 + j] = e; sum += e; }
        float inv = 1.0f / sum;
        for (int j = 0; j < 64; ++j) S[t * 64 + j] *= inv;
    }
    __syncthreads();

    {
        int i  = t >> 2;
        int d0 = (t & 3) * 16;
        size_t orow = ((size_t)(b * NTOK + 1 + POS(i))) * C_ + h * 64;
        for (int d = d0; d < d0 + 16; ++d) {
            float accv = 0.f;
#pragma unroll 8
            for (int j = 0; j < 64; ++j)
                accv += S[i * 64 + j] * us2f(vs[j * 64 + d]);
            xcat[orow + d] = f2us(accv);
        }
    }
#undef POS
}

// ---------------------------------------------------------------------------
// Cls attention, split-K partials: block = (head, split, bb). 256 keys/block,
// one key per thread. Writes {acc[64], m, sum} per (b,h,split).
// ---------------------------------------------------------------------------
__global__ __launch_bounds__(256) void cls_part(
    const unsigned short* __restrict__ qkv2,
    const unsigned short* __restrict__ m16, const float* __restrict__ m32,
    const unsigned short* __restrict__ g16, const float* __restrict__ g32,
    const int* __restrict__ flagp,
    float* __restrict__ part,      // [B][NH][NSPLIT][68]
    int b0)
{
    __shared__ float q[64];
    __shared__ float e[256];
    __shared__ float red[256];
    __shared__ float osum[4][64];
    __shared__ float Mv, Sv;

    const int h  = blockIdx.x;
    const int sp = blockIdx.y;
    const int bb = blockIdx.z;
    const int b  = b0 + bb;
    const int t  = threadIdx.x;
    const int f  = *flagp;
    const unsigned short* qkvb = qkv2 + (size_t)bb * NTOK * 2304;

    if (t < 64) q[t] = us2f(qkvb[h * 64 + t]);   // row 0 = cls token
    __syncthreads();

    const int j = sp * 256 + t;                   // key 0..4095
    const unsigned short* krow = &qkvb[(size_t)(1 + j) * 2304 + 768 + h * 64];
    float s = 0.f;
#pragma unroll
    for (int dd = 0; dd < 8; ++dd) {
        us8 kv8 = *reinterpret_cast<const us8*>(&krow[dd * 8]);
#pragma unroll
        for (int ee = 0; ee < 8; ++ee) s += q[dd * 8 + ee] * us2f(kv8[ee]);
    }
    s *= 0.125f;
    {
        size_t mi = ((size_t)b * HW_ + j) * C_;
        size_t gi = ((size_t)b * NH_ + h) * HW_ + j;
        float tokj = f ? m32[mi] : us2f(m16[mi]);
        float gmj  = f ? g32[gi] : us2f(g16[gi]);
        if (tokj * gmj == 0.0f) s = NEGV;
    }

    red[t] = s; __syncthreads();
    for (int k2 = 128; k2 > 0; k2 >>= 1) { if (t < k2) red[t] = fmaxf(red[t], red[t + k2]); __syncthreads(); }
    const float m = red[0]; __syncthreads();

    float ev = __expf(s - m);
    e[t] = ev; red[t] = ev; __syncthreads();
    for (int k2 = 128; k2 > 0; k2 >>= 1) { if (t < k2) red[t] += red[t + k2]; __syncthreads(); }
    if (t == 0) { Mv = m; Sv = red[0]; }

    // PV: wave wv covers keys [wv*64, wv*64+64), lane = output dim
    const int wv = t >> 6, l = t & 63;
    float accv = 0.f;
    const unsigned short* vbase =
        &qkvb[(size_t)(1 + sp * 256 + wv * 64) * 2304 + 1536 + h * 64 + l];
    for (int kk = 0; kk < 64; ++kk)
        accv += e[wv * 64 + kk] * us2f(vbase[(size_t)kk * 2304]);
    osum[wv][l] = accv;
    __syncthreads();

    const size_t pi = ((size_t)(b * NH_ + h) * NSPLIT + sp) * 68;
    if (t < 64)
        part[pi + t] = osum[0][t] + osum[1][t] + osum[2][t] + osum[3][t];
    if (t == 64 + 0) part[pi + 64] = Mv;
    if (t == 64 + 1) part[pi + 65] = Sv;
}

// ---------------------------------------------------------------------------
// Combine split partials (log-sum-exp merge) -> xcat cls rows (bf16)
// ---------------------------------------------------------------------------
__global__ __launch_bounds__(64) void cls_reduce(
    const float* __restrict__ part, unsigned short* __restrict__ xcat)
{
    const int h = blockIdx.x, b = blockIdx.y, t = threadIdx.x;
    const float* pb = &part[((size_t)(b * NH_ + h) * NSPLIT) * 68];
    float gm = -1e30f;
    for (int i = 0; i < NSPLIT; ++i) gm = fmaxf(gm, pb[i * 68 + 64]);
    float S = 0.f, acc = 0.f;
    for (int i = 0; i < NSPLIT; ++i) {
        float w = __expf(pb[i * 68 + 64] - gm);
        S   += pb[i * 68 + 65] * w;
        acc += pb[i * 68 + t]  * w;
    }
    xcat[(size_t)(b * NTOK) * C_ + h * 64 + t] = f2us(acc / S);
}

// ---------------------------------------------------------------------------
// v_cls GEMV + broadcast-add, reading xcat (d_out) and writing xcatc (ws):
// replaces the 50 MB memcpy. Also copies cls rows. Grid (96, 4 row-splits).
// ---------------------------------------------------------------------------
__global__ __launch_bounds__(256) void add_vcls(
    const unsigned short* __restrict__ xcat, unsigned short* __restrict__ xcatc,
    const unsigned short* __restrict__ kv16, const float* __restrict__ kv32,
    const int* __restrict__ flagp)
{
    __shared__ float xr[768];
    __shared__ float psum[4][64];
    __shared__ float vc[64];

    const int blk = blockIdx.x;
    const int rsp = blockIdx.y;
    const int b   = blk / 12;
    const int c0  = (blk % 12) * 64;
    const int t   = threadIdx.x;
    const int f   = *flagp;

    for (int it = 0; it < 3; ++it) {
        int k = t + it * 256;
        xr[k] = us2f(xcat[(size_t)(b * NTOK) * C_ + k]);
    }
    __syncthreads();

    const int cc = t & 63, kq = t >> 6;
    float p = 0.f;
    for (int k = kq * 192; k < kq * 192 + 192; ++k) {
        size_t wi = (size_t)k * 1536 + 768 + c0 + cc;
        p += xr[k] * (f ? kv32[wi] : us2f(kv16[wi]));
    }
    psum[kq][cc] = p;
    __syncthreads();
    if (t < 64) vc[t] = psum[0][t] + psum[1][t] + psum[2][t] + psum[3][t];
    __syncthreads();

    const int ch8  = (t & 7) * 8;
    const int rsub = t >> 3;
    for (int it = 0; it < 32; ++it) {
        int row = rsp * 1024 + it * 32 + rsub;
        size_t off = (size_t)(b * NTOK + 1 + row) * C_ + c0 + ch8;
        us8 vv = *reinterpret_cast<const us8*>(&xcat[off]);
#pragma unroll
        for (int e2 = 0; e2 < 8; ++e2)
            vv[e2] = f2us(us2f(vv[e2]) + vc[ch8 + e2]);
        *reinterpret_cast<us8*>(&xcatc[off]) = vv;
    }
    if (rsp == 0 && t < 64)
        xcatc[(size_t)(b * NTOK) * C_ + c0 + t] = xcat[(size_t)(b * NTOK) * C_ + c0 + t];
}

// ---------------------------------------------------------------------------
// Workspace plan:
//   [0,128)                    flag
//   [128, 37,758,080)          qkv_2b   (2-batch slab, reused 4x)
//   [37,758,080, 41,297,024)   qkv_wT   (dead after last qkv GEMM)
//   [41,297,024, 41,714,816)   cls partials (dead after cls_reduce)
//   [128, 50,344,064)          xcatc    (written by add_vcls, after all above die)
//   [50,344,064, 51,523,712)   pwT      (proj_w^T bf16 — only if ws_size permits;
//                                        lives OUTSIDE the xcatc span so it
//                                        survives through the final GEMM)
// xcat (pre-proj activations) lives in d_out until add_vcls moves it to ws.
// ---------------------------------------------------------------------------
extern "C" void kernel_launch(void* const* d_in, const int* in_sizes, int n_in,
                              void* d_out, int out_size, void* d_ws, size_t ws_size,
                              hipStream_t stream)
{
    const unsigned short* x16  = (const unsigned short*)d_in[0];
    const float*          x32  = (const float*)d_in[0];
    const unsigned short* m16  = (const unsigned short*)d_in[1];
    const float*          m32  = (const float*)d_in[1];
    const unsigned short* g16  = (const unsigned short*)d_in[2];
    const float*          g32  = (const float*)d_in[2];
    const unsigned short* qw16 = (const unsigned short*)d_in[3];
    const float*          qw32 = (const float*)d_in[3];
    const unsigned short* kv16 = (const unsigned short*)d_in[4];
    const float*          kv32 = (const float*)d_in[4];
    const unsigned short* pw16 = (const unsigned short*)d_in[5];
    const float*          pw32 = (const float*)d_in[5];
    const unsigned short* pb16 = (const unsigned short*)d_in[6];
    const float*          pb32 = (const float*)d_in[6];

    char* ws = (char*)d_ws;
    int*            flag   = (int*)ws;
    unsigned short* qkv_2b = (unsigned short*)(ws + 128);
    unsigned short* qkv_wT = (unsigned short*)(ws + 37758080);
    float*          part   = (float*)(ws + 41297024);
    unsigned short* xcatc  = (unsigned short*)(ws + 128);
    unsigned short* pwT    = (unsigned short*)(ws + 50344064);
    unsigned short* xcat   = (unsigned short*)d_out;

    const bool fastproj = (ws_size >= (size_t)51523712);

    detect_dtype<<<1, 256, 0, stream>>>((const unsigned int*)d_in[0], flag);
    transpose_w<<<(2304 * 768 + 255) / 256, 256, 0, stream>>>(
        qw16, qw32, flag, qkv_wT, 768, 2304);
    if (fastproj)
        transpose_w<<<(768 * 768 + 255) / 256, 256, 0, stream>>>(
            pw16, pw32, flag, pwT, 768, 768);

    for (int b0 = 0; b0 < B_; b0 += 2) {
        gemm_bt<<<dim3(18, 65), 256, 0, stream>>>(
            x16, x32, flag, qkv_wT,
            nullptr, nullptr, nullptr,
            qkv_2b, nullptr,
            2 * NTOK, 2304, 768, (long)b0 * NTOK);
        win_attn<<<dim3(64, 12, 2), 256, 0, stream>>>(qkv_2b, m16, m32, flag, xcat, b0);
        cls_part<<<dim3(12, NSPLIT, 2), 256, 0, stream>>>(
            qkv_2b, m16, m32, g16, g32, flag, part, b0);
    }

    cls_reduce<<<dim3(12, 8), 64, 0, stream>>>(part, xcat);
    add_vcls<<<dim3(96, 4), 256, 0, stream>>>(xcat, xcatc, kv16, kv32, flag);

    if (fastproj) {
        gemm_bt<<<dim3(6, 257), 256, 0, stream>>>(
            xcatc, nullptr, nullptr, pwT,
            pb16, pb32, flag,
            d_out, flag,
            MTOT, 768, 768, 0);
    } else {
        gemm_univ<<<dim3(6, 257), 256, 0, stream>>>(
            xcatc, nullptr, nullptr, pw16, pw32, flag, 1,
            pb16, pb32, d_out, flag,
            MTOT, 768, 768, 0);
    }
}

// Round 2
// 799.426 us; speedup vs baseline: 1.7840x; 1.5455x over previous
//
#include <hip/hip_runtime.h>

// Problem constants: B=8, C=768, NH=12, WS=8, NC=1, H=W=64
#define B_    8
#define C_    768
#define NH_   12
#define HW_   4096
#define NTOK  4097
#define MTOT  32776         // B_ * NTOK
#define NEGV  (-10000.0f)
#define NSPLIT 16

typedef __bf16 bf16x8 __attribute__((ext_vector_type(8)));
typedef float  f32x4  __attribute__((ext_vector_type(4)));
typedef unsigned short us8 __attribute__((ext_vector_type(8)));

// addrspace casts for global_load_lds
#define GLB(p) ((const __attribute__((address_space(1))) void*)(p))
#define LDS(p) ((__attribute__((address_space(3))) void*)(p))

__device__ __forceinline__ float us2f(unsigned short u) {
    unsigned int v = ((unsigned int)u) << 16;
    float f; __builtin_memcpy(&f, &v, 4);
    return f;
}
__device__ __forceinline__ unsigned short f2us(float f) {
    unsigned int v; __builtin_memcpy(&v, &f, 4);
    v += 0x7FFFu + ((v >> 16) & 1u);   // RNE
    return (unsigned short)(v >> 16);
}

// ---------------------------------------------------------------------------
// Runtime dtype detect (flag=1 -> fp32 inputs).
// ---------------------------------------------------------------------------
__global__ __launch_bounds__(256) void detect_dtype(
    const unsigned int* __restrict__ xw, int* __restrict__ flag)
{
    __shared__ int s[256];
    int t = threadIdx.x, cnt = 0;
    for (int i = t; i < 4096; i += 256) {
        unsigned e = (xw[i] >> 23) & 0xFFu;
        cnt += (e >= 64u && e <= 191u) ? 1 : 0;
    }
    s[t] = cnt; __syncthreads();
    for (int k = 128; k > 0; k >>= 1) { if (t < k) s[t] += s[t + k]; __syncthreads(); }
    if (t == 0) *flag = (s[0] > 2048) ? 1 : 0;
}

// ---------------------------------------------------------------------------
// Generic weight transpose: src (Kd x Nd, flag dtype) -> dst (Nd x Kd, bf16)
// ---------------------------------------------------------------------------
__global__ __launch_bounds__(256) void transpose_w(
    const unsigned short* __restrict__ s16, const float* __restrict__ s32,
    const int* __restrict__ flagp, unsigned short* __restrict__ dst,
    int Kd, int Nd)
{
    int o = blockIdx.x * 256 + threadIdx.x;
    if (o >= Kd * Nd) return;
    int n = o / Kd, k = o % Kd;
    dst[o] = (*flagp) ? f2us(s32[(size_t)k * Nd + n]) : s16[(size_t)k * Nd + n];
}

// ---------------------------------------------------------------------------
// Fast GEMM, m97 structure: 128x128x32 tile, 4 waves, 16x16x32 bf16 MFMA,
// LINEAR [128][32] LDS tiles staged via global_load_lds dwordx4.
// ---------------------------------------------------------------------------
__global__ __launch_bounds__(256) void gemm_bt(
    const unsigned short* __restrict__ A16, const float* __restrict__ A32,
    const int* __restrict__ aflagp,
    const unsigned short* __restrict__ BT,
    const unsigned short* __restrict__ bias16, const float* __restrict__ bias32,
    const int* __restrict__ bflagp,
    void* __restrict__ Cout, const int* __restrict__ oflagp,
    int M, int Nd, int K, long arow0)
{
    __shared__ __align__(16) unsigned short As[128 * 32];   // 8 KB
    __shared__ __align__(16) unsigned short Bs[128 * 32];   // 8 KB

    const int fa = aflagp ? *aflagp : 0;
    const int fb = bflagp ? *bflagp : 0;
    const int fo = oflagp ? *oflagp : 0;

    const int t    = threadIdx.x;
    const int m0   = blockIdx.y * 128;
    const int n0   = blockIdx.x * 128;
    const int wave = t >> 6;
    const int lane = t & 63;
    const int wm   = (wave >> 1) * 64;
    const int wn   = (wave & 1) * 64;
    const int frow = lane & 15;
    const int koff = (lane >> 4) * 8;

    f32x4 acc[4][4];
#pragma unroll
    for (int i = 0; i < 4; ++i)
#pragma unroll
        for (int j = 0; j < 4; ++j) acc[i][j] = (f32x4)0.0f;

    const int sr = t >> 2;
    const int sc = (t & 3) * 8;

    int ga0 = m0 + sr;       if (ga0 >= M)  ga0 = M - 1;
    int ga1 = m0 + sr + 64;  if (ga1 >= M)  ga1 = M - 1;
    int gb0 = n0 + sr;       if (gb0 >= Nd) gb0 = Nd - 1;
    int gb1 = n0 + sr + 64;  if (gb1 >= Nd) gb1 = Nd - 1;

    const unsigned short* a0p = A16 + (size_t)(arow0 + ga0) * K + sc;
    const unsigned short* a1p = A16 + (size_t)(arow0 + ga1) * K + sc;
    const float*          a0f = A32 + (size_t)(arow0 + ga0) * K + sc;
    const float*          a1f = A32 + (size_t)(arow0 + ga1) * K + sc;
    const unsigned short* b0p = BT + (size_t)gb0 * K + sc;
    const unsigned short* b1p = BT + (size_t)gb1 * K + sc;

    unsigned short* asd = &As[t * 8];
    unsigned short* bsd = &Bs[t * 8];

    for (int k0 = 0; k0 < K; k0 += 32) {
        if (fa) {   // fp32 A fallback: register stage + convert (wave-uniform)
            unsigned short tmp[8];
#pragma unroll
            for (int e = 0; e < 8; ++e) tmp[e] = f2us(a0f[k0 + e]);
            *reinterpret_cast<us8*>(&As[sr * 32 + sc]) = *reinterpret_cast<us8*>(tmp);
#pragma unroll
            for (int e = 0; e < 8; ++e) tmp[e] = f2us(a1f[k0 + e]);
            *reinterpret_cast<us8*>(&As[(sr + 64) * 32 + sc]) = *reinterpret_cast<us8*>(tmp);
        } else {
            __builtin_amdgcn_global_load_lds(GLB(a0p + k0), LDS(asd),        16, 0, 0);
            __builtin_amdgcn_global_load_lds(GLB(a1p + k0), LDS(asd + 2048), 16, 0, 0);
        }
        __builtin_amdgcn_global_load_lds(GLB(b0p + k0), LDS(bsd),        16, 0, 0);
        __builtin_amdgcn_global_load_lds(GLB(b1p + k0), LDS(bsd + 2048), 16, 0, 0);
        __syncthreads();

        bf16x8 af[4], bfr[4];
#pragma unroll
        for (int i = 0; i < 4; ++i)
            af[i] = *reinterpret_cast<const bf16x8*>(&As[(wm + i * 16 + frow) * 32 + koff]);
#pragma unroll
        for (int j = 0; j < 4; ++j)
            bfr[j] = *reinterpret_cast<const bf16x8*>(&Bs[(wn + j * 16 + frow) * 32 + koff]);
#pragma unroll
        for (int i = 0; i < 4; ++i)
#pragma unroll
            for (int j = 0; j < 4; ++j)
                acc[i][j] = __builtin_amdgcn_mfma_f32_16x16x32_bf16(af[i], bfr[j], acc[i][j], 0, 0, 0);
        __syncthreads();
    }

    const int crow = (lane >> 4) * 4;
    const int ccol = lane & 15;
    unsigned short* C16 = (unsigned short*)Cout;
    float*          C32 = (float*)Cout;
#pragma unroll
    for (int i = 0; i < 4; ++i)
#pragma unroll
        for (int j = 0; j < 4; ++j) {
            int gn = n0 + wn + j * 16 + ccol;
            float bv = 0.0f;
            if (bias16) bv = fb ? bias32[gn] : us2f(bias16[gn]);
#pragma unroll
            for (int r = 0; r < 4; ++r) {
                int gm = m0 + wm + i * 16 + crow + r;
                if (gm < M) {
                    float v = acc[i][j][r] + bv;
                    if (fo) C32[(size_t)gm * Nd + gn] = v;
                    else    C16[(size_t)gm * Nd + gn] = f2us(v);
                }
            }
        }
}

// ---------------------------------------------------------------------------
// Universal GEMM (fallback for proj when ws too small for pwT).
// ---------------------------------------------------------------------------
#define LSTR 40   // 32+8 pad; 80 B rows, 16B-aligned

__global__ __launch_bounds__(256) void gemm_univ(
    const unsigned short* __restrict__ A16, const float* __restrict__ A32,
    const int* __restrict__ aflagp,
    const unsigned short* __restrict__ B16, const float* __restrict__ B32,
    const int* __restrict__ bflagp, int btmode,
    const unsigned short* __restrict__ bias16, const float* __restrict__ bias32,
    void* __restrict__ Cout, const int* __restrict__ oflagp,
    int M, int Nd, int K, long arow0)
{
    __shared__ __align__(16) unsigned short As[128 * LSTR];
    __shared__ __align__(16) unsigned short Bs[128 * LSTR];

    const int fa = aflagp ? *aflagp : 0;
    const int fb = bflagp ? *bflagp : 0;
    const int fo = oflagp ? *oflagp : 0;

    const int t    = threadIdx.x;
    const int m0   = blockIdx.y * 128;
    const int n0   = blockIdx.x * 128;
    const int wave = t >> 6;
    const int lane = t & 63;
    const int wm   = (wave >> 1) * 64;
    const int wn   = (wave & 1) * 64;
    const int frow = lane & 15;
    const int koff = (lane >> 4) * 8;

    f32x4 acc[4][4];
#pragma unroll
    for (int i = 0; i < 4; ++i)
#pragma unroll
        for (int j = 0; j < 4; ++j) acc[i][j] = (f32x4)0.0f;

    const int sr = t >> 2;
    const int sc = (t & 3) * 8;

    for (int k0 = 0; k0 < K; k0 += 32) {
#pragma unroll
        for (int it = 0; it < 2; ++it) {
            int r = sr + it * 64;
            int gl = m0 + r; if (gl >= M) gl = M - 1;
            size_t grow = (size_t)(arow0 + gl);
            if (fa) {
                const float* p = &A32[grow * K + k0 + sc];
                unsigned short tmp[8];
#pragma unroll
                for (int e = 0; e < 8; ++e) tmp[e] = f2us(p[e]);
                *reinterpret_cast<us8*>(&As[r * LSTR + sc]) = *reinterpret_cast<us8*>(tmp);
            } else {
                *reinterpret_cast<bf16x8*>(&As[r * LSTR + sc]) =
                    *reinterpret_cast<const bf16x8*>(&A16[grow * K + k0 + sc]);
            }
        }
        if (btmode == 0) {
#pragma unroll
            for (int it = 0; it < 2; ++it) {
                int r = sr + it * 64;
                int gn = n0 + r; if (gn >= Nd) gn = Nd - 1;
                *reinterpret_cast<bf16x8*>(&Bs[r * LSTR + sc]) =
                    *reinterpret_cast<const bf16x8*>(&B16[(size_t)gn * K + k0 + sc]);
            }
        } else {
            const int kr = t >> 3;
            const int nc = (t & 7) * 16;
            if (fb) {
                const float* p = &B32[(size_t)(k0 + kr) * Nd + n0 + nc];
#pragma unroll
                for (int e = 0; e < 16; ++e) Bs[(nc + e) * LSTR + kr] = f2us(p[e]);
            } else {
                const unsigned short* p = &B16[(size_t)(k0 + kr) * Nd + n0 + nc];
#pragma unroll
                for (int e = 0; e < 16; ++e) Bs[(nc + e) * LSTR + kr] = p[e];
            }
        }
        __syncthreads();

        bf16x8 af[4], bfr[4];
#pragma unroll
        for (int i = 0; i < 4; ++i)
            af[i] = *reinterpret_cast<const bf16x8*>(&As[(wm + i * 16 + frow) * LSTR + koff]);
#pragma unroll
        for (int j = 0; j < 4; ++j)
            bfr[j] = *reinterpret_cast<const bf16x8*>(&Bs[(wn + j * 16 + frow) * LSTR + koff]);
#pragma unroll
        for (int i = 0; i < 4; ++i)
#pragma unroll
            for (int j = 0; j < 4; ++j)
                acc[i][j] = __builtin_amdgcn_mfma_f32_16x16x32_bf16(af[i], bfr[j], acc[i][j], 0, 0, 0);
        __syncthreads();
    }

    const int crow = (lane >> 4) * 4;
    const int ccol = lane & 15;
    unsigned short* C16 = (unsigned short*)Cout;
    float*          C32 = (float*)Cout;
#pragma unroll
    for (int i = 0; i < 4; ++i)
#pragma unroll
        for (int j = 0; j < 4; ++j) {
            int gn = n0 + wn + j * 16 + ccol;
            float bv = 0.0f;
            if (bias16) bv = fb ? bias32[gn] : us2f(bias16[gn]);
#pragma unroll
            for (int r = 0; r < 4; ++r) {
                int gm = m0 + wm + i * 16 + crow + r;
                if (gm < M) {
                    float v = acc[i][j][r] + bv;
                    if (fo) C32[(size_t)gm * Nd + gn] = v;
                    else    C16[(size_t)gm * Nd + gn] = f2us(v);
                }
            }
        }
}

// ---------------------------------------------------------------------------
// Window attention, MFMA version. Block = (window, head, bb), 4 waves.
// QK^T and PV use the verified 16x16x32 bf16 fragment mapping from gemm_bt.
// LDS strides: bf16 tiles 72 (144 B rows), S f32 65 (2-way banks max).
// ps (bf16 P matrix) overlays qs (dead after QK^T).
// ---------------------------------------------------------------------------
#define AST 72    // bf16 tile stride (elements)
#define SST 65    // S f32 stride (elements)

__global__ __launch_bounds__(256) void win_attn(
    const unsigned short* __restrict__ qkv2,
    const unsigned short* __restrict__ m16, const float* __restrict__ m32,
    const int* __restrict__ flagp,
    unsigned short* __restrict__ xcat, int b0)
{
    __shared__ __align__(16) unsigned short qs[64 * AST];   // reused as ps
    __shared__ __align__(16) unsigned short ks[64 * AST];
    __shared__ __align__(16) unsigned short vsT[64 * AST];  // [d][key]
    __shared__ float S[64 * SST];
    __shared__ float tok[64];

    const int w  = blockIdx.x;
    const int h  = blockIdx.y;
    const int bb = blockIdx.z;
    const int b  = b0 + bb;
    const int hb = w >> 3, wb = w & 7;
    const int t  = threadIdx.x;
    const int f  = *flagp;
    const unsigned short* qkvb = qkv2 + (size_t)bb * NTOK * 2304;

#define POS(i) ((hb * 8 + ((i) >> 3)) * 64 + wb * 8 + ((i) & 7))

#pragma unroll
    for (int it = 0; it < 2; ++it) {
        int i = (t >> 3) + it * 32;
        int d = (t & 7) * 8;
        size_t row = (size_t)(1 + POS(i)) * 2304;
        bf16x8 qv = *reinterpret_cast<const bf16x8*>(&qkvb[row + 0    + h * 64 + d]);
        bf16x8 kv = *reinterpret_cast<const bf16x8*>(&qkvb[row + 768  + h * 64 + d]);
        us8    vv = *reinterpret_cast<const us8*>  (&qkvb[row + 1536 + h * 64 + d]);
        *reinterpret_cast<bf16x8*>(&qs[i * AST + d]) = qv;
        *reinterpret_cast<bf16x8*>(&ks[i * AST + d]) = kv;
#pragma unroll
        for (int e = 0; e < 8; ++e) vsT[(d + e) * AST + i] = vv[e];
    }
    if (t < 64) {
        size_t mi = ((size_t)b * HW_ + POS(t)) * C_;
        tok[t] = f ? m32[mi] : us2f(m16[mi]);
    }
    __syncthreads();

    const int wave = t >> 6;
    const int lane = t & 63;
    const int wm   = (wave >> 1) * 32;
    const int wn   = (wave & 1) * 32;
    const int frow = lane & 15;
    const int koff = (lane >> 4) * 8;
    const int crow = (lane >> 4) * 4;
    const int ccol = lane & 15;

    // ---- QK^T: S = Q @ K^T (wave tile 32x32, K=64) ----
    {
        f32x4 acc[2][2];
#pragma unroll
        for (int i = 0; i < 2; ++i)
#pragma unroll
            for (int j = 0; j < 2; ++j) acc[i][j] = (f32x4)0.0f;
#pragma unroll
        for (int kk = 0; kk < 64; kk += 32) {
            bf16x8 af[2], bfr[2];
#pragma unroll
            for (int i = 0; i < 2; ++i)
                af[i] = *reinterpret_cast<const bf16x8*>(&qs[(wm + i * 16 + frow) * AST + kk + koff]);
#pragma unroll
            for (int j = 0; j < 2; ++j)
                bfr[j] = *reinterpret_cast<const bf16x8*>(&ks[(wn + j * 16 + frow) * AST + kk + koff]);
#pragma unroll
            for (int i = 0; i < 2; ++i)
#pragma unroll
                for (int j = 0; j < 2; ++j)
                    acc[i][j] = __builtin_amdgcn_mfma_f32_16x16x32_bf16(af[i], bfr[j], acc[i][j], 0, 0, 0);
        }
#pragma unroll
        for (int i = 0; i < 2; ++i)
#pragma unroll
            for (int j = 0; j < 2; ++j)
#pragma unroll
                for (int r = 0; r < 4; ++r)
                    S[(wm + i * 16 + crow + r) * SST + wn + j * 16 + ccol] = acc[i][j][r];
    }
    __syncthreads();

    // ---- softmax: 4 lanes per row, 16 cols each ----
    {
        const int r = t >> 2;
        const int q = t & 3;
        const float tr = tok[r];
        float sv[16];
        float mx = -1e30f;
#pragma unroll
        for (int e = 0; e < 16; ++e) {
            int c = q * 16 + e;
            float s = S[r * SST + c] * 0.125f;
            if (tr * tok[c] == 0.0f) s = NEGV;
            sv[e] = s;
            mx = fmaxf(mx, s);
        }
        mx = fmaxf(mx, __shfl_xor(mx, 1));
        mx = fmaxf(mx, __shfl_xor(mx, 2));
        float sum = 0.f;
#pragma unroll
        for (int e = 0; e < 16; ++e) { sv[e] = __expf(sv[e] - mx); sum += sv[e]; }
        sum += __shfl_xor(sum, 1);
        sum += __shfl_xor(sum, 2);
        const float inv = 1.0f / sum;
        unsigned short* ps = qs;   // overlay (qs dead after QK^T)
        us8 o0, o1;
#pragma unroll
        for (int e = 0; e < 8; ++e) { o0[e] = f2us(sv[e] * inv); o1[e] = f2us(sv[8 + e] * inv); }
        *reinterpret_cast<us8*>(&ps[r * AST + q * 16])     = o0;
        *reinterpret_cast<us8*>(&ps[r * AST + q * 16 + 8]) = o1;
    }
    __syncthreads();

    // ---- PV: O = P @ V (A = ps rows=queries, B = vsT rows=d, K=64 keys) ----
    {
        const unsigned short* ps = qs;
        f32x4 acc[2][2];
#pragma unroll
        for (int i = 0; i < 2; ++i)
#pragma unroll
            for (int j = 0; j < 2; ++j) acc[i][j] = (f32x4)0.0f;
#pragma unroll
        for (int kk = 0; kk < 64; kk += 32) {
            bf16x8 af[2], bfr[2];
#pragma unroll
            for (int i = 0; i < 2; ++i)
                af[i] = *reinterpret_cast<const bf16x8*>(&ps[(wm + i * 16 + frow) * AST + kk + koff]);
#pragma unroll
            for (int j = 0; j < 2; ++j)
                bfr[j] = *reinterpret_cast<const bf16x8*>(&vsT[(wn + j * 16 + frow) * AST + kk + koff]);
#pragma unroll
            for (int i = 0; i < 2; ++i)
#pragma unroll
                for (int j = 0; j < 2; ++j)
                    acc[i][j] = __builtin_amdgcn_mfma_f32_16x16x32_bf16(af[i], bfr[j], acc[i][j], 0, 0, 0);
        }
#pragma unroll
        for (int i = 0; i < 2; ++i)
#pragma unroll
            for (int j = 0; j < 2; ++j)
#pragma unroll
                for (int r = 0; r < 4; ++r) {
                    int qrow = wm + i * 16 + crow + r;
                    int dcol = wn + j * 16 + ccol;
                    xcat[(size_t)(b * NTOK + 1 + POS(qrow)) * C_ + h * 64 + dcol] =
                        f2us(acc[i][j][r]);
                }
    }
#undef POS
}

// ---------------------------------------------------------------------------
// Cls attention, split-K partials (unchanged).
// ---------------------------------------------------------------------------
__global__ __launch_bounds__(256) void cls_part(
    const unsigned short* __restrict__ qkv2,
    const unsigned short* __restrict__ m16, const float* __restrict__ m32,
    const unsigned short* __restrict__ g16, const float* __restrict__ g32,
    const int* __restrict__ flagp,
    float* __restrict__ part,      // [B][NH][NSPLIT][68]
    int b0)
{
    __shared__ float q[64];
    __shared__ float e[256];
    __shared__ float red[256];
    __shared__ float osum[4][64];
    __shared__ float Mv, Sv;

    const int h  = blockIdx.x;
    const int sp = blockIdx.y;
    const int bb = blockIdx.z;
    const int b  = b0 + bb;
    const int t  = threadIdx.x;
    const int f  = *flagp;
    const unsigned short* qkvb = qkv2 + (size_t)bb * NTOK * 2304;

    if (t < 64) q[t] = us2f(qkvb[h * 64 + t]);   // row 0 = cls token
    __syncthreads();

    const int j = sp * 256 + t;                   // key 0..4095
    const unsigned short* krow = &qkvb[(size_t)(1 + j) * 2304 + 768 + h * 64];
    float s = 0.f;
#pragma unroll
    for (int dd = 0; dd < 8; ++dd) {
        us8 kv8 = *reinterpret_cast<const us8*>(&krow[dd * 8]);
#pragma unroll
        for (int ee = 0; ee < 8; ++ee) s += q[dd * 8 + ee] * us2f(kv8[ee]);
    }
    s *= 0.125f;
    {
        size_t mi = ((size_t)b * HW_ + j) * C_;
        size_t gi = ((size_t)b * NH_ + h) * HW_ + j;
        float tokj = f ? m32[mi] : us2f(m16[mi]);
        float gmj  = f ? g32[gi] : us2f(g16[gi]);
        if (tokj * gmj == 0.0f) s = NEGV;
    }

    red[t] = s; __syncthreads();
    for (int k2 = 128; k2 > 0; k2 >>= 1) { if (t < k2) red[t] = fmaxf(red[t], red[t + k2]); __syncthreads(); }
    const float m = red[0]; __syncthreads();

    float ev = __expf(s - m);
    e[t] = ev; red[t] = ev; __syncthreads();
    for (int k2 = 128; k2 > 0; k2 >>= 1) { if (t < k2) red[t] += red[t + k2]; __syncthreads(); }
    if (t == 0) { Mv = m; Sv = red[0]; }

    const int wv = t >> 6, l = t & 63;
    float accv = 0.f;
    const unsigned short* vbase =
        &qkvb[(size_t)(1 + sp * 256 + wv * 64) * 2304 + 1536 + h * 64 + l];
    for (int kk = 0; kk < 64; ++kk)
        accv += e[wv * 64 + kk] * us2f(vbase[(size_t)kk * 2304]);
    osum[wv][l] = accv;
    __syncthreads();

    const size_t pi = ((size_t)(b * NH_ + h) * NSPLIT + sp) * 68;
    if (t < 64)
        part[pi + t] = osum[0][t] + osum[1][t] + osum[2][t] + osum[3][t];
    if (t == 64 + 0) part[pi + 64] = Mv;
    if (t == 64 + 1) part[pi + 65] = Sv;
}

// ---------------------------------------------------------------------------
// Combine split partials (log-sum-exp merge) -> xcat cls rows (bf16)
// ---------------------------------------------------------------------------
__global__ __launch_bounds__(64) void cls_reduce(
    const float* __restrict__ part, unsigned short* __restrict__ xcat)
{
    const int h = blockIdx.x, b = blockIdx.y, t = threadIdx.x;
    const float* pb = &part[((size_t)(b * NH_ + h) * NSPLIT) * 68];
    float gm = -1e30f;
    for (int i = 0; i < NSPLIT; ++i) gm = fmaxf(gm, pb[i * 68 + 64]);
    float S = 0.f, acc = 0.f;
    for (int i = 0; i < NSPLIT; ++i) {
        float w = __expf(pb[i * 68 + 64] - gm);
        S   += pb[i * 68 + 65] * w;
        acc += pb[i * 68 + t]  * w;
    }
    xcat[(size_t)(b * NTOK) * C_ + h * 64 + t] = f2us(acc / S);
}

// ---------------------------------------------------------------------------
// v_cls GEMV + broadcast-add (unchanged).
// ---------------------------------------------------------------------------
__global__ __launch_bounds__(256) void add_vcls(
    const unsigned short* __restrict__ xcat, unsigned short* __restrict__ xcatc,
    const unsigned short* __restrict__ kv16, const float* __restrict__ kv32,
    const int* __restrict__ flagp)
{
    __shared__ float xr[768];
    __shared__ float psum[4][64];
    __shared__ float vc[64];

    const int blk = blockIdx.x;
    const int rsp = blockIdx.y;
    const int b   = blk / 12;
    const int c0  = (blk % 12) * 64;
    const int t   = threadIdx.x;
    const int f   = *flagp;

    for (int it = 0; it < 3; ++it) {
        int k = t + it * 256;
        xr[k] = us2f(xcat[(size_t)(b * NTOK) * C_ + k]);
    }
    __syncthreads();

    const int cc = t & 63, kq = t >> 6;
    float p = 0.f;
    for (int k = kq * 192; k < kq * 192 + 192; ++k) {
        size_t wi = (size_t)k * 1536 + 768 + c0 + cc;
        p += xr[k] * (f ? kv32[wi] : us2f(kv16[wi]));
    }
    psum[kq][cc] = p;
    __syncthreads();
    if (t < 64) vc[t] = psum[0][t] + psum[1][t] + psum[2][t] + psum[3][t];
    __syncthreads();

    const int ch8  = (t & 7) * 8;
    const int rsub = t >> 3;
    for (int it = 0; it < 32; ++it) {
        int row = rsp * 1024 + it * 32 + rsub;
        size_t off = (size_t)(b * NTOK + 1 + row) * C_ + c0 + ch8;
        us8 vv = *reinterpret_cast<const us8*>(&xcat[off]);
#pragma unroll
        for (int e2 = 0; e2 < 8; ++e2)
            vv[e2] = f2us(us2f(vv[e2]) + vc[ch8 + e2]);
        *reinterpret_cast<us8*>(&xcatc[off]) = vv;
    }
    if (rsp == 0 && t < 64)
        xcatc[(size_t)(b * NTOK) * C_ + c0 + t] = xcat[(size_t)(b * NTOK) * C_ + c0 + t];
}

// ---------------------------------------------------------------------------
// Workspace plan:
//   [0,128)                    flag
//   [128, 37,758,080)          qkv_2b   (2-batch slab, reused 4x)
//   [37,758,080, 41,297,024)   qkv_wT   (dead after last qkv GEMM)
//   [41,297,024, 41,714,816)   cls partials (dead after cls_reduce)
//   [128, 50,344,064)          xcatc    (written by add_vcls, after all above die)
//   [50,344,064, 51,523,712)   pwT      (proj_w^T bf16, survives to final GEMM)
// ---------------------------------------------------------------------------
extern "C" void kernel_launch(void* const* d_in, const int* in_sizes, int n_in,
                              void* d_out, int out_size, void* d_ws, size_t ws_size,
                              hipStream_t stream)
{
    const unsigned short* x16  = (const unsigned short*)d_in[0];
    const float*          x32  = (const float*)d_in[0];
    const unsigned short* m16  = (const unsigned short*)d_in[1];
    const float*          m32  = (const float*)d_in[1];
    const unsigned short* g16  = (const unsigned short*)d_in[2];
    const float*          g32  = (const float*)d_in[2];
    const unsigned short* qw16 = (const unsigned short*)d_in[3];
    const float*          qw32 = (const float*)d_in[3];
    const unsigned short* kv16 = (const unsigned short*)d_in[4];
    const float*          kv32 = (const float*)d_in[4];
    const unsigned short* pw16 = (const unsigned short*)d_in[5];
    const float*          pw32 = (const float*)d_in[5];
    const unsigned short* pb16 = (const unsigned short*)d_in[6];
    const float*          pb32 = (const float*)d_in[6];

    char* ws = (char*)d_ws;
    int*            flag   = (int*)ws;
    unsigned short* qkv_2b = (unsigned short*)(ws + 128);
    unsigned short* qkv_wT = (unsigned short*)(ws + 37758080);
    float*          part   = (float*)(ws + 41297024);
    unsigned short* xcatc  = (unsigned short*)(ws + 128);
    unsigned short* pwT    = (unsigned short*)(ws + 50344064);
    unsigned short* xcat   = (unsigned short*)d_out;

    const bool fastproj = (ws_size >= (size_t)51523712);

    detect_dtype<<<1, 256, 0, stream>>>((const unsigned int*)d_in[0], flag);
    transpose_w<<<(2304 * 768 + 255) / 256, 256, 0, stream>>>(
        qw16, qw32, flag, qkv_wT, 768, 2304);
    if (fastproj)
        transpose_w<<<(768 * 768 + 255) / 256, 256, 0, stream>>>(
            pw16, pw32, flag, pwT, 768, 768);

    for (int b0 = 0; b0 < B_; b0 += 2) {
        gemm_bt<<<dim3(18, 65), 256, 0, stream>>>(
            x16, x32, flag, qkv_wT,
            nullptr, nullptr, nullptr,
            qkv_2b, nullptr,
            2 * NTOK, 2304, 768, (long)b0 * NTOK);
        win_attn<<<dim3(64, 12, 2), 256, 0, stream>>>(qkv_2b, m16, m32, flag, xcat, b0);
        cls_part<<<dim3(12, NSPLIT, 2), 256, 0, stream>>>(
            qkv_2b, m16, m32, g16, g32, flag, part, b0);
    }

    cls_reduce<<<dim3(12, 8), 64, 0, stream>>>(part, xcat);
    add_vcls<<<dim3(96, 4), 256, 0, stream>>>(xcat, xcatc, kv16, kv32, flag);

    if (fastproj) {
        gemm_bt<<<dim3(6, 257), 256, 0, stream>>>(
            xcatc, nullptr, nullptr, pwT,
            pb16, pb32, flag,
            d_out, flag,
            MTOT, 768, 768, 0);
    } else {
        gemm_univ<<<dim3(6, 257), 256, 0, stream>>>(
            xcatc, nullptr, nullptr, pw16, pw32, flag, 1,
            pb16, pb32, d_out, flag,
            MTOT, 768, 768, 0);
    }
}